// Round 7
// baseline (33634.143 us; speedup 1.0000x reference)
//
#include <hip/hip_runtime.h>
#include <hip/hip_bf16.h>

typedef __hip_bfloat16 bf16;

#define TM 64
#define TN 64
#define TK 16
#define LDP 68  // padded leading dim; float4-aligned, 2-way bank alias max

__device__ __forceinline__ float ldE(const float* p) { return *p; }
__device__ __forceinline__ float ldE(const bf16* p)  { return (float)*p; }
__device__ __forceinline__ void stC(float* p, float v) { *p = v; }
__device__ __forceinline__ void stC(bf16* p, float v)  { *p = __float2bfloat16(v); }

// NaN-proof activations (clamp = no-op on sane data).
__device__ __forceinline__ float sigm(float x) {
    x = fminf(fmaxf(x, -40.f), 40.f);
    return 1.f / (1.f + expf(-x));
}
__device__ __forceinline__ float tanh_s(float x) {
    x = fminf(fmaxf(x, -20.f), 20.f);
    float e = expf(2.f * x);
    return 1.f - 2.f / (e + 1.f);
}

// Batched GEMM: C[d] = A[d] (MxK, row-major) @ W[d]^T (W is NcxK, row-major).
template <typename AT, typename WT, typename CT>
__global__ __launch_bounds__(256) void gemm_aw(
    const AT* __restrict__ A, long sAd,
    const WT* __restrict__ W, long sWd,
    CT* __restrict__ C, long sCd,
    int M, int Nc, int K)
{
    __shared__ alignas(16) float As[TK][LDP];
    __shared__ alignas(16) float Ws[TK][LDP];
    const int d = blockIdx.z;
    A += (long)d * sAd; W += (long)d * sWd; C += (long)d * sCd;
    const int m0 = blockIdx.y * TM;
    const int n0 = blockIdx.x * TN;
    const int tid = threadIdx.x;
    const int tx = tid & 15, ty = tid >> 4;

    float acc[4][4] = {};
    for (int k0 = 0; k0 < K; k0 += TK) {
#pragma unroll
        for (int i = 0; i < 4; ++i) {
            int e = tid + i * 256;
            int m = e >> 4;
            int kk = e & 15;
            float va = 0.f, vw = 0.f;
            if (m0 + m < M && k0 + kk < K) va = ldE(&A[(long)(m0 + m) * K + k0 + kk]);
            if (n0 + m < Nc && k0 + kk < K) vw = ldE(&W[(long)(n0 + m) * K + k0 + kk]);
            As[kk][m] = va;
            Ws[kk][m] = vw;
        }
        __syncthreads();
#pragma unroll
        for (int kk = 0; kk < TK; ++kk) {
            float4 a4 = *reinterpret_cast<const float4*>(&As[kk][ty * 4]);
            float4 b4 = *reinterpret_cast<const float4*>(&Ws[kk][tx * 4]);
            float a[4] = {a4.x, a4.y, a4.z, a4.w};
            float b[4] = {b4.x, b4.y, b4.z, b4.w};
#pragma unroll
            for (int i = 0; i < 4; ++i)
#pragma unroll
                for (int j = 0; j < 4; ++j)
                    acc[i][j] += a[i] * b[j];
        }
        __syncthreads();
    }
#pragma unroll
    for (int i = 0; i < 4; ++i) {
        int m = m0 + ty * 4 + i;
        if (m >= M) continue;
#pragma unroll
        for (int j = 0; j < 4; ++j) {
            int n = n0 + tx * 4 + j;
            if (n < Nc) stC(&C[(long)m * Nc + n], acc[i][j]);
        }
    }
}

// ---- device-scope grid barrier (sense via monotonically increasing gen) ----
__device__ __forceinline__ void gridbar(int* cnt, int* gen)
{
    __syncthreads();
    if (threadIdx.x == 0) {
        __threadfence();  // release: make this block's writes device-visible
        int g = __hip_atomic_load(gen, __ATOMIC_RELAXED, __HIP_MEMORY_SCOPE_AGENT);
        int a = __hip_atomic_fetch_add(cnt, 1, __ATOMIC_ACQ_REL, __HIP_MEMORY_SCOPE_AGENT);
        if (a == (int)gridDim.x - 1) {
            __hip_atomic_store(cnt, 0, __ATOMIC_RELAXED, __HIP_MEMORY_SCOPE_AGENT);
            __hip_atomic_fetch_add(gen, 1, __ATOMIC_RELEASE, __HIP_MEMORY_SCOPE_AGENT);
        } else {
            while (__hip_atomic_load(gen, __ATOMIC_ACQUIRE, __HIP_MEMORY_SCOPE_AGENT) == g)
                __builtin_amdgcn_s_sleep(2);
        }
        __threadfence();  // acquire: invalidate L1 so h reads see other CUs' writes
    }
    __syncthreads();
}

// ---- persistent sentence-GRU scan: one chunk of 60 steps, both directions ----
// Grid MUST be 256 blocks x 256 threads (co-residency for the grid barrier).
// Block (d, jb) owns hidden units [c0, c1) (5-6 of 700); Whh slice lives in LDS
// (lane-uniform reads -> LDS broadcast, conflict-free). h double-buffered by
// global step parity. One grid barrier per step.
#define SCH 60
__global__ __launch_bounds__(256) void sent_scan(
    const float* __restrict__ Whh,   // [2, 2100, 700]
    const float* __restrict__ bih,   // [2, 2100]
    const float* __restrict__ bhh,   // [2, 2100]
    const bf16*  __restrict__ xw,    // [2, SCH, 128, 2100] input gates (no bias)
    float* hb0, float* hb1,          // h buffers [2,128,700] (start & end in hb0)
    bf16*  __restrict__ y,           // [120,128,1400] or nullptr
    int kbase, int tb0, int tb1,
    int* bar_cnt, int* bar_gen)
{
    const int H = 700, G = 2100, B = 128;
    const int bi = blockIdx.x;
    const int d  = bi >> 7;
    const int jb = bi & 127;
    const int c0 = (jb * H) >> 7;
    const int c1 = ((jb + 1) * H) >> 7;
    const int NC = c1 - c0;                    // 5 or 6
    const int t = threadIdx.x;
    const int n = t & 127;
    const int half = t >> 7;                   // wave-uniform (waves 0,1 / 2,3)
    const int h0cnt = (NC + 1) >> 1;
    const int jstart = half ? h0cnt : 0;
    const int jcount = half ? (NC - h0cnt) : h0cnt;   // <= 3

    __shared__ alignas(16) float Wlds[3][6][704];

    for (int i = t; i < 3 * 6 * 704; i += 256) ((float*)Wlds)[i] = 0.f;
    __syncthreads();
    for (int i = t; i < 3 * NC * 700; i += 256) {
        int g  = i / (NC * 700);
        int r  = i % (NC * 700);
        int jc = r / 700;
        int k  = r % 700;
        Wlds[g][jc][k] = Whh[((long)d * G + g * H + c0 + jc) * (long)H + k];
    }
    // per-thread biases for its columns (safe-clamped index for unused slots)
    float br_[3], bz_[3], bn_[3], pr_[3], pz_[3], pn_[3];
#pragma unroll
    for (int jc = 0; jc < 3; ++jc) {
        int j = c0 + jstart + ((jc < jcount) ? jc : 0);
        br_[jc] = bih[(long)d * G + j];
        bz_[jc] = bih[(long)d * G + H + j];
        bn_[jc] = bih[(long)d * G + 2 * H + j];
        pr_[jc] = bhh[(long)d * G + j];
        pz_[jc] = bhh[(long)d * G + H + j];
        pn_[jc] = bhh[(long)d * G + 2 * H + j];
    }
    __syncthreads();

    for (int s = 0; s < SCH; ++s) {
        const int kg = kbase + s;
        const int t_eff = (d == 0) ? kg : (119 - kg);
        const int t_loc = t_eff - ((d == 0) ? tb0 : tb1);
        const float* hp = ((kg & 1) ? hb1 : hb0) + (long)d * B * H;  // read
        float*       hn = ((kg & 1) ? hb0 : hb1) + (long)d * B * H;  // write

        // phase 1: gh accumulation (acc[jc][gate])
        float acc[3][3] = {};
        const float4* hrow = (const float4*)(hp + n * H);
        float4 h4 = hrow[0];
        for (int kc = 0; kc < 175; ++kc) {
            float4 hc = h4;
            if (kc < 174) h4 = hrow[kc + 1];
#pragma unroll
            for (int jc = 0; jc < 3; ++jc) {
                const float* wr0 = &Wlds[0][jstart + jc][kc * 4];
                const float* wr1 = &Wlds[1][jstart + jc][kc * 4];
                const float* wr2 = &Wlds[2][jstart + jc][kc * 4];
                float4 w0 = *(const float4*)wr0;
                float4 w1 = *(const float4*)wr1;
                float4 w2 = *(const float4*)wr2;
                acc[jc][0] += hc.x * w0.x + hc.y * w0.y + hc.z * w0.z + hc.w * w0.w;
                acc[jc][1] += hc.x * w1.x + hc.y * w1.y + hc.z * w1.z + hc.w * w1.w;
                acc[jc][2] += hc.x * w2.x + hc.y * w2.y + hc.z * w2.z + hc.w * w2.w;
            }
        }

        // phase 2: gate math (thread-local), h update, y write
        const bf16* xp = xw + (((long)d * SCH + t_loc) * B + n) * (long)G;
#pragma unroll
        for (int jc = 0; jc < 3; ++jc) {
            if (jc >= jcount) break;
            int j = c0 + jstart + jc;
            float xr = (float)xp[j]         + br_[jc];
            float xz = (float)xp[H + j]     + bz_[jc];
            float xn = (float)xp[2 * H + j] + bn_[jc];
            float r  = sigm(xr + acc[jc][0] + pr_[jc]);
            float z  = sigm(xz + acc[jc][1] + pz_[jc]);
            float nn = tanh_s(xn + r * (acc[jc][2] + pn_[jc]));
            float hold = hp[n * H + j];
            float hnew = (1.f - z) * nn + z * hold;
            hn[n * H + j] = hnew;
            if (y) y[((long)t_eff * B + n) * 1400 + d * 700 + j] = __float2bfloat16(hnew);
        }
        gridbar(bar_cnt, bar_gen);
    }
}

// Word layer-0 GRU step: input gates gathered from embW[tok] (= emb @ Wih0^T).
__global__ void gru_step_word0(
    const int* __restrict__ x,      // [S,T,B]
    const bf16* __restrict__ embW,  // [2, V, 3H]
    const float* __restrict__ gh,   // [2, N, 3H]
    const float* __restrict__ bih,  // [2, 3H]
    const float* __restrict__ bhh,  // [2, 3H]
    float* __restrict__ h,          // [2, N, H]
    bf16* __restrict__ y,           // [T, N, 2H]
    int S, int T, int B, int V, int H, int k)
{
    const int N = S * B;
    long idx = (long)blockIdx.x * 256 + threadIdx.x;
    if (idx >= 2ll * N * H) return;
    int j = idx % H;
    int n = (idx / H) % N;
    int d = idx / ((long)N * H);
    int G = 3 * H;
    int t_eff = (d == 0) ? k : (T - 1 - k);
    int s = n / B, b = n % B;
    int tok = x[((long)s * T + t_eff) * B + b];
    tok = max(0, min(V - 1, tok));

    const bf16*  xp = embW + ((long)d * V + tok) * G;
    const float* gp = gh + ((long)d * N + n) * G;
    const float* bi = bih + (long)d * G;
    const float* bh = bhh + (long)d * G;

    float xr = (float)xp[j]         + bi[j];
    float xz = (float)xp[H + j]     + bi[H + j];
    float xn = (float)xp[2 * H + j] + bi[2 * H + j];
    float hr = gp[j]         + bh[j];
    float hz = gp[H + j]     + bh[H + j];
    float hn = gp[2 * H + j] + bh[2 * H + j];

    float r = sigm(xr + hr);
    float z = sigm(xz + hz);
    float nn = tanh_s(xn + r * hn);

    long hidx = ((long)d * N + n) * H + j;
    float hnew = (1.f - z) * nn + z * h[hidx];
    h[hidx] = hnew;
    y[((long)t_eff * N + n) * (2 * H) + (long)d * H + j] = __float2bfloat16(hnew);
}

// Generic GRU step; xw holds ONE timestep per direction (word layer 1).
__global__ void gru_step1(
    const bf16* __restrict__ xw,
    int tb0, int tb1, int Cbuf,
    const float* __restrict__ gh,  // [2, N, 3H]
    const float* __restrict__ bih, // [2, 3H]
    const float* __restrict__ bhh, // [2, 3H]
    float* __restrict__ h,         // [2, N, H]
    bf16* __restrict__ y,          // or nullptr
    int N, int H, int L, int k)
{
    long idx = (long)blockIdx.x * 256 + threadIdx.x;
    if (idx >= 2ll * N * H) return;
    int j = idx % H;
    int n = (idx / H) % N;
    int d = idx / ((long)N * H);
    int G = 3 * H;
    int t_eff = (d == 0) ? k : (L - 1 - k);
    int t_local = t_eff - ((d == 0) ? tb0 : tb1);

    const bf16*  xp = xw + (((long)d * Cbuf + t_local) * N + n) * G;
    const float* gp = gh + ((long)d * N + n) * G;
    const float* bi = bih + (long)d * G;
    const float* bh = bhh + (long)d * G;

    float xr = (float)xp[j]         + bi[j];
    float xz = (float)xp[H + j]     + bi[H + j];
    float xn = (float)xp[2 * H + j] + bi[2 * H + j];
    float hr = gp[j]         + bh[j];
    float hz = gp[H + j]     + bh[H + j];
    float hn = gp[2 * H + j] + bh[2 * H + j];

    float r = sigm(xr + hr);
    float z = sigm(xz + hz);
    float nn = tanh_s(xn + r * hn);

    long hidx = ((long)d * N + n) * H + j;
    float hnew = (1.f - z) * nn + z * h[hidx];
    h[hidx] = hnew;
    if (y) y[((long)t_eff * N + n) * (2 * H) + (long)d * H + j] = __float2bfloat16(hnew);
}

// out[n, 4H] = [ha_d0 | ha_d1 | hb_d0 | hb_d1]
template <typename OT>
__global__ void concat4(const float* __restrict__ ha, const float* __restrict__ hb,
                        OT* __restrict__ out, int N, int H)
{
    long idx = (long)blockIdx.x * 256 + threadIdx.x;
    int C4 = 4 * H;
    if (idx >= (long)N * C4) return;
    int c = idx % C4;
    long n = idx / C4;
    int blk = c / H, j = c % H;
    const float* src = (blk < 2) ? ha : hb;
    int dd = blk & 1;
    stC(&out[idx], src[((long)dd * N + n) * H + j]);
}

extern "C" void kernel_launch(void* const* d_in, const int* in_sizes, int n_in,
                              void* d_out, int out_size, void* d_ws, size_t ws_size,
                              hipStream_t stream)
{
    const int S = 120, T = 10, B = 128, E = 80, HW = 75, HS = 700, V = 30000;
    const int Nw = S * B;            // 15360
    const int Gw = 3 * HW;           // 225
    const int Gs = 3 * HS;           // 2100
    const int CH = SCH;              // 60
    (void)in_sizes; (void)n_in; (void)out_size; (void)ws_size;

    const int*   x       = (const int*)d_in[0];
    const float* emb     = (const float*)d_in[1];
    const float* we_Wih0 = (const float*)d_in[2],  *we_Whh0 = (const float*)d_in[3];
    const float* we_bih0 = (const float*)d_in[4],  *we_bhh0 = (const float*)d_in[5];
    const float* we_Wih1 = (const float*)d_in[6],  *we_Whh1 = (const float*)d_in[7];
    const float* we_bih1 = (const float*)d_in[8],  *we_bhh1 = (const float*)d_in[9];
    const float* se_Wih0 = (const float*)d_in[10], *se_Whh0 = (const float*)d_in[11];
    const float* se_bih0 = (const float*)d_in[12], *se_bhh0 = (const float*)d_in[13];
    const float* se_Wih1 = (const float*)d_in[14], *se_Whh1 = (const float*)d_in[15];
    const float* se_bih1 = (const float*)d_in[16], *se_bhh1 = (const float*)d_in[17];

    // ---- arenas (142.2 MB, same as R6) ----
    char* ws = (char*)d_ws;
    const size_t szA = 9216000;    // words bf16 [Nw,300]
    const size_t szB = 46080000;   // y0w bf16 -> y0s bf16 [S*B,1400]
    const size_t szCDE = 68472000; // word: embW | gh_w | xw_w1 ; sent: xw_ch
    const size_t szF = 9216000;    // h_w0 -> (unused in sentence)
    const size_t szG = 9216000;    // h_w1 -> h_s bufs + barrier
    char* pA = ws;
    char* pB = pA + szA;
    char* pC = pB + szB;
    char* pF = pC + szCDE;
    char* pG = pF + szF;
    const size_t total = szA + szB + szCDE + szF + szG;

    bf16*  words  = (bf16*)pA;
    bf16*  y0w    = (bf16*)pB;
    bf16*  y0s    = (bf16*)pB;
    bf16*  embW   = (bf16*)pC;
    float* gh_w   = (float*)(pC + 27000000);
    bf16*  xw_w1  = (bf16*)(pC + 27000000 + 27648000);
    bf16*  xw_ch  = (bf16*)pC;                        // sentence phase overlay
    float* h_w0   = (float*)pF;
    float* h_w1   = (float*)pG;
    // sentence h double-buffers + barrier (overlay pG after h_w1 dies)
    float* hs0a = (float*)pG;
    float* hs0b = (float*)(pG + 716800);
    float* hs1a = (float*)(pG + 1433600);
    float* hs1b = (float*)(pG + 2150400);
    int*   bar  = (int*)(pG + 3000000);               // [0]=cnt, [1]=gen

    hipMemsetAsync(ws, 0, total, stream);  // poison kill + h0 = 0

    auto grid = [](int M, int Nc) {
        return dim3((Nc + TN - 1) / TN, (M + TM - 1) / TM, 2);
    };

    // ===================== word encoder =====================
    gemm_aw<float, float, bf16><<<grid(V, Gw), 256, 0, stream>>>(
        emb, 0, we_Wih0, (long)Gw * E, embW, (long)V * Gw, V, Gw, E);
    for (int k = 0; k < T; ++k) {
        gemm_aw<float, float, float><<<grid(Nw, Gw), 256, 0, stream>>>(
            h_w0, (long)Nw * HW, we_Whh0, (long)Gw * HW, gh_w, (long)Nw * Gw, Nw, Gw, HW);
        long tot = 2ll * Nw * HW;
        gru_step_word0<<<(tot + 255) / 256, 256, 0, stream>>>(
            x, embW, gh_w, we_bih0, we_bhh0, h_w0, y0w, S, T, B, V, HW, k);
    }
    for (int k = 0; k < T; ++k) {
        gemm_aw<bf16, float, bf16><<<grid(Nw, Gw), 256, 0, stream>>>(
            y0w + (long)k * Nw * 2 * HW, (long)(T - 1 - 2 * k) * Nw * 2 * HW,
            we_Wih1, (long)Gw * (2 * HW), xw_w1, (long)Nw * Gw, Nw, Gw, 2 * HW);
        gemm_aw<float, float, float><<<grid(Nw, Gw), 256, 0, stream>>>(
            h_w1, (long)Nw * HW, we_Whh1, (long)Gw * HW, gh_w, (long)Nw * Gw, Nw, Gw, HW);
        long tot = 2ll * Nw * HW;
        gru_step1<<<(tot + 255) / 256, 256, 0, stream>>>(
            xw_w1, k, T - 1 - k, 1, gh_w, we_bih1, we_bhh1, h_w1, nullptr, Nw, HW, T, k);
    }
    {
        long tot = (long)Nw * 4 * HW;
        concat4<bf16><<<(tot + 255) / 256, 256, 0, stream>>>(h_w0, h_w1, words, Nw, HW);
    }

    // ===================== sentence encoder (persistent scans) ==============
    hipMemsetAsync(pG, 0, 3000256, stream);  // h bufs + barrier zeroed

    for (int c = 0; c < 2; ++c) {
        int tb0 = c * CH, tb1 = S - c * CH - CH;
        gemm_aw<bf16, float, bf16><<<grid(CH * B, Gs), 256, 0, stream>>>(
            words + (long)tb0 * B * (4 * HW), (long)(tb1 - tb0) * B * (4 * HW),
            se_Wih0, (long)Gs * (4 * HW), xw_ch, (long)CH * B * Gs, CH * B, Gs, 4 * HW);
        sent_scan<<<256, 256, 0, stream>>>(
            se_Whh0, se_bih0, se_bhh0, xw_ch, hs0a, hs0b, y0s,
            c * CH, tb0, tb1, bar, bar + 1);
    }
    for (int c = 0; c < 2; ++c) {
        int tb0 = c * CH, tb1 = S - c * CH - CH;
        gemm_aw<bf16, float, bf16><<<grid(CH * B, Gs), 256, 0, stream>>>(
            y0s + (long)tb0 * B * (2 * HS), (long)(tb1 - tb0) * B * (2 * HS),
            se_Wih1, (long)Gs * (2 * HS), xw_ch, (long)CH * B * Gs, CH * B, Gs, 2 * HS);
        sent_scan<<<256, 256, 0, stream>>>(
            se_Whh1, se_bih1, se_bhh1, xw_ch, hs1a, hs1b, nullptr,
            c * CH, tb0, tb1, bar, bar + 1);
    }

    // out[1, B, 4*HS] = [sf0 | sb0 | sf1 | sb1]  (float32)
    {
        long tot = (long)B * 4 * HS;
        concat4<float><<<(tot + 255) / 256, 256, 0, stream>>>(hs0a, hs1a, (float*)d_out, B, HS);
    }
}

// Round 8
// 21957.370 us; speedup vs baseline: 1.5318x; 1.5318x over previous
//
#include <hip/hip_runtime.h>
#include <hip/hip_bf16.h>

typedef __hip_bfloat16 bf16;

#define TM 64
#define TN 64
#define TK 16
#define LDP 68  // padded leading dim; float4-aligned, 2-way bank alias max

__device__ __forceinline__ float ldE(const float* p) { return *p; }
__device__ __forceinline__ float ldE(const bf16* p)  { return (float)*p; }
__device__ __forceinline__ void stC(float* p, float v) { *p = v; }
__device__ __forceinline__ void stC(bf16* p, float v)  { *p = __float2bfloat16(v); }

// NaN-proof activations (clamp = no-op on sane data).
__device__ __forceinline__ float sigm(float x) {
    x = fminf(fmaxf(x, -40.f), 40.f);
    return 1.f / (1.f + expf(-x));
}
__device__ __forceinline__ float tanh_s(float x) {
    x = fminf(fmaxf(x, -20.f), 20.f);
    float e = expf(2.f * x);
    return 1.f - 2.f / (e + 1.f);
}

// Batched GEMM: C[d] = A[d] (MxK, row-major) @ W[d]^T (W is NcxK, row-major).
template <typename AT, typename WT, typename CT>
__global__ __launch_bounds__(256) void gemm_aw(
    const AT* __restrict__ A, long sAd,
    const WT* __restrict__ W, long sWd,
    CT* __restrict__ C, long sCd,
    int M, int Nc, int K)
{
    __shared__ alignas(16) float As[TK][LDP];
    __shared__ alignas(16) float Ws[TK][LDP];
    const int d = blockIdx.z;
    A += (long)d * sAd; W += (long)d * sWd; C += (long)d * sCd;
    const int m0 = blockIdx.y * TM;
    const int n0 = blockIdx.x * TN;
    const int tid = threadIdx.x;
    const int tx = tid & 15, ty = tid >> 4;

    float acc[4][4] = {};
    for (int k0 = 0; k0 < K; k0 += TK) {
#pragma unroll
        for (int i = 0; i < 4; ++i) {
            int e = tid + i * 256;
            int m = e >> 4;
            int kk = e & 15;
            float va = 0.f, vw = 0.f;
            if (m0 + m < M && k0 + kk < K) va = ldE(&A[(long)(m0 + m) * K + k0 + kk]);
            if (n0 + m < Nc && k0 + kk < K) vw = ldE(&W[(long)(n0 + m) * K + k0 + kk]);
            As[kk][m] = va;
            Ws[kk][m] = vw;
        }
        __syncthreads();
#pragma unroll
        for (int kk = 0; kk < TK; ++kk) {
            float4 a4 = *reinterpret_cast<const float4*>(&As[kk][ty * 4]);
            float4 b4 = *reinterpret_cast<const float4*>(&Ws[kk][tx * 4]);
            float a[4] = {a4.x, a4.y, a4.z, a4.w};
            float b[4] = {b4.x, b4.y, b4.z, b4.w};
#pragma unroll
            for (int i = 0; i < 4; ++i)
#pragma unroll
                for (int j = 0; j < 4; ++j)
                    acc[i][j] += a[i] * b[j];
        }
        __syncthreads();
    }
#pragma unroll
    for (int i = 0; i < 4; ++i) {
        int m = m0 + ty * 4 + i;
        if (m >= M) continue;
#pragma unroll
        for (int j = 0; j < 4; ++j) {
            int n = n0 + tx * 4 + j;
            if (n < Nc) stC(&C[(long)m * Nc + n], acc[i][j]);
        }
    }
}

// ---- fused sentence GRU step: gh GEMV + gates + h update, one kernel/step ----
// Grid: (100 j-tiles of 7, 1, 2 dirs) = 200 blocks x 256 threads.
// Block stages its 21x700 f32 Whh slice into LDS (59 KB, warm-L2 source).
// Thread (n2 = t&63, q = t>>6): covers n in {n2, n2+64}, local j in
// {2q, 2q+1} (q<3) or {6} (q==3). Wlds reads are wave-uniform -> broadcast
// (free); h reads hit L2 (716 KB working set, no fences -> stays warm).
// Coherence across steps comes from kernel boundaries. h double-buffered.
#define SCH 60
#define JT 7
__global__ __launch_bounds__(256) void step_fused(
    const float* __restrict__ Whh,   // [2, 2100, 700]
    const float* __restrict__ bih,   // [2, 2100]
    const float* __restrict__ bhh,   // [2, 2100]
    const bf16*  __restrict__ xw,    // [2, SCH, 128, 2100] input gates (no bias)
    const float* __restrict__ hR,    // read  h buf [2,128,700]
    float*       __restrict__ hW,    // write h buf [2,128,700]
    bf16*        __restrict__ y,     // [120,128,1400] or nullptr
    int kg, int tb0, int tb1)
{
    const int H = 700, G = 2100, B = 128;
    const int d  = blockIdx.z;
    const int j0 = blockIdx.x * JT;
    const int t  = threadIdx.x;
    const int n2 = t & 63;
    const int q  = t >> 6;                    // wave-uniform
    const int jb = q * 2;                     // 0,2,4,6
    const int jcnt = (q == 3) ? 1 : 2;

    __shared__ alignas(16) float Wl[21 * 704];   // [g*7+jl][k], 59,136 B

    for (int i = t; i < 21 * 700; i += 256) {
        int g = i / 4900, r = i % 4900, jl = r / 700, k = r % 700;
        Wl[(g * 7 + jl) * 704 + k] = Whh[((long)d * G + g * H + j0 + jl) * H + k];
    }
    __syncthreads();

    const int t_eff = (d == 0) ? kg : (119 - kg);
    const int t_loc = t_eff - ((d == 0) ? tb0 : tb1);
    const float* hr = hR + (long)d * B * H;
    float*       hw = hW + (long)d * B * H;

    float acc[2][2][3] = {};
    const float4* h0p = (const float4*)(hr + n2 * H);
    const float4* h1p = (const float4*)(hr + (n2 + 64) * H);
    float4 a0 = h0p[0], a1 = h1p[0];
    for (int kc = 0; kc < 175; ++kc) {
        float4 c0 = a0, c1 = a1;
        if (kc < 174) { a0 = h0p[kc + 1]; a1 = h1p[kc + 1]; }
#pragma unroll
        for (int jl = 0; jl < 2; ++jl) {
            if (jl >= jcnt) break;
#pragma unroll
            for (int g = 0; g < 3; ++g) {
                float4 w = *(const float4*)&Wl[(g * 7 + jb + jl) * 704 + kc * 4];
                acc[0][jl][g] += c0.x * w.x + c0.y * w.y + c0.z * w.z + c0.w * w.w;
                acc[1][jl][g] += c1.x * w.x + c1.y * w.y + c1.z * w.z + c1.w * w.w;
            }
        }
    }

    // gates + h update (thread-local; no cross-thread data)
    for (int jl = 0; jl < jcnt; ++jl) {
        int j = j0 + jb + jl;
        float br = bih[(long)d * G + j];
        float bz = bih[(long)d * G + H + j];
        float bn = bih[(long)d * G + 2 * H + j];
        float pr = bhh[(long)d * G + j];
        float pz = bhh[(long)d * G + H + j];
        float pn = bhh[(long)d * G + 2 * H + j];
#pragma unroll
        for (int ni = 0; ni < 2; ++ni) {
            int n = n2 + ni * 64;
            const bf16* xp = xw + (((long)d * SCH + t_loc) * B + n) * (long)G;
            float xr = (float)xp[j]         + br;
            float xz = (float)xp[H + j]     + bz;
            float xn = (float)xp[2 * H + j] + bn;
            float r  = sigm(xr + acc[ni][jl][0] + pr);
            float z  = sigm(xz + acc[ni][jl][1] + pz);
            float nn = tanh_s(xn + r * (acc[ni][jl][2] + pn));
            float hold = hr[n * H + j];
            float hnew = (1.f - z) * nn + z * hold;
            hw[n * H + j] = hnew;
            if (y) y[((long)t_eff * B + n) * 1400 + d * 700 + j] = __float2bfloat16(hnew);
        }
    }
}

// Word layer-0 GRU step: input gates gathered from embW[tok] (= emb @ Wih0^T).
__global__ void gru_step_word0(
    const int* __restrict__ x,      // [S,T,B]
    const bf16* __restrict__ embW,  // [2, V, 3H]
    const float* __restrict__ gh,   // [2, N, 3H]
    const float* __restrict__ bih,  // [2, 3H]
    const float* __restrict__ bhh,  // [2, 3H]
    float* __restrict__ h,          // [2, N, H]
    bf16* __restrict__ y,           // [T, N, 2H]
    int S, int T, int B, int V, int H, int k)
{
    const int N = S * B;
    long idx = (long)blockIdx.x * 256 + threadIdx.x;
    if (idx >= 2ll * N * H) return;
    int j = idx % H;
    int n = (idx / H) % N;
    int d = idx / ((long)N * H);
    int G = 3 * H;
    int t_eff = (d == 0) ? k : (T - 1 - k);
    int s = n / B, b = n % B;
    int tok = x[((long)s * T + t_eff) * B + b];
    tok = max(0, min(V - 1, tok));

    const bf16*  xp = embW + ((long)d * V + tok) * G;
    const float* gp = gh + ((long)d * N + n) * G;
    const float* bi = bih + (long)d * G;
    const float* bh = bhh + (long)d * G;

    float xr = (float)xp[j]         + bi[j];
    float xz = (float)xp[H + j]     + bi[H + j];
    float xn = (float)xp[2 * H + j] + bi[2 * H + j];
    float hr = gp[j]         + bh[j];
    float hz = gp[H + j]     + bh[H + j];
    float hn = gp[2 * H + j] + bh[2 * H + j];

    float r = sigm(xr + hr);
    float z = sigm(xz + hz);
    float nn = tanh_s(xn + r * hn);

    long hidx = ((long)d * N + n) * H + j;
    float hnew = (1.f - z) * nn + z * h[hidx];
    h[hidx] = hnew;
    y[((long)t_eff * N + n) * (2 * H) + (long)d * H + j] = __float2bfloat16(hnew);
}

// Generic GRU step; xw holds ONE timestep per direction (word layer 1).
__global__ void gru_step1(
    const bf16* __restrict__ xw,
    int tb0, int tb1, int Cbuf,
    const float* __restrict__ gh,  // [2, N, 3H]
    const float* __restrict__ bih, // [2, 3H]
    const float* __restrict__ bhh, // [2, 3H]
    float* __restrict__ h,         // [2, N, H]
    bf16* __restrict__ y,          // or nullptr
    int N, int H, int L, int k)
{
    long idx = (long)blockIdx.x * 256 + threadIdx.x;
    if (idx >= 2ll * N * H) return;
    int j = idx % H;
    int n = (idx / H) % N;
    int d = idx / ((long)N * H);
    int G = 3 * H;
    int t_eff = (d == 0) ? k : (L - 1 - k);
    int t_local = t_eff - ((d == 0) ? tb0 : tb1);

    const bf16*  xp = xw + (((long)d * Cbuf + t_local) * N + n) * G;
    const float* gp = gh + ((long)d * N + n) * G;
    const float* bi = bih + (long)d * G;
    const float* bh = bhh + (long)d * G;

    float xr = (float)xp[j]         + bi[j];
    float xz = (float)xp[H + j]     + bi[H + j];
    float xn = (float)xp[2 * H + j] + bi[2 * H + j];
    float hr = gp[j]         + bh[j];
    float hz = gp[H + j]     + bh[H + j];
    float hn = gp[2 * H + j] + bh[2 * H + j];

    float r = sigm(xr + hr);
    float z = sigm(xz + hz);
    float nn = tanh_s(xn + r * hn);

    long hidx = ((long)d * N + n) * H + j;
    float hnew = (1.f - z) * nn + z * h[hidx];
    h[hidx] = hnew;
    if (y) y[((long)t_eff * N + n) * (2 * H) + (long)d * H + j] = __float2bfloat16(hnew);
}

// out[n, 4H] = [ha_d0 | ha_d1 | hb_d0 | hb_d1]
template <typename OT>
__global__ void concat4(const float* __restrict__ ha, const float* __restrict__ hb,
                        OT* __restrict__ out, int N, int H)
{
    long idx = (long)blockIdx.x * 256 + threadIdx.x;
    int C4 = 4 * H;
    if (idx >= (long)N * C4) return;
    int c = idx % C4;
    long n = idx / C4;
    int blk = c / H, j = c % H;
    const float* src = (blk < 2) ? ha : hb;
    int dd = blk & 1;
    stC(&out[idx], src[((long)dd * N + n) * H + j]);
}

extern "C" void kernel_launch(void* const* d_in, const int* in_sizes, int n_in,
                              void* d_out, int out_size, void* d_ws, size_t ws_size,
                              hipStream_t stream)
{
    const int S = 120, T = 10, B = 128, E = 80, HW = 75, HS = 700, V = 30000;
    const int Nw = S * B;            // 15360
    const int Gw = 3 * HW;           // 225
    const int Gs = 3 * HS;           // 2100
    const int CH = SCH;              // 60
    (void)in_sizes; (void)n_in; (void)out_size; (void)ws_size;

    const int*   x       = (const int*)d_in[0];
    const float* emb     = (const float*)d_in[1];
    const float* we_Wih0 = (const float*)d_in[2],  *we_Whh0 = (const float*)d_in[3];
    const float* we_bih0 = (const float*)d_in[4],  *we_bhh0 = (const float*)d_in[5];
    const float* we_Wih1 = (const float*)d_in[6],  *we_Whh1 = (const float*)d_in[7];
    const float* we_bih1 = (const float*)d_in[8],  *we_bhh1 = (const float*)d_in[9];
    const float* se_Wih0 = (const float*)d_in[10], *se_Whh0 = (const float*)d_in[11];
    const float* se_bih0 = (const float*)d_in[12], *se_bhh0 = (const float*)d_in[13];
    const float* se_Wih1 = (const float*)d_in[14], *se_Whh1 = (const float*)d_in[15];
    const float* se_bih1 = (const float*)d_in[16], *se_bhh1 = (const float*)d_in[17];

    // ---- arenas (142.2 MB, same as R6) ----
    char* ws = (char*)d_ws;
    const size_t szA = 9216000;    // words bf16 [Nw,300]
    const size_t szB = 46080000;   // y0w bf16 -> y0s bf16 [S*B,1400]
    const size_t szCDE = 68472000; // word: embW | gh_w | xw_w1 ; sent: xw_ch
    const size_t szF = 9216000;    // h_w0
    const size_t szG = 9216000;    // h_w1 -> sentence h double-buffers
    char* pA = ws;
    char* pB = pA + szA;
    char* pC = pB + szB;
    char* pF = pC + szCDE;
    char* pG = pF + szF;
    const size_t total = szA + szB + szCDE + szF + szG;

    bf16*  words  = (bf16*)pA;
    bf16*  y0w    = (bf16*)pB;
    bf16*  y0s    = (bf16*)pB;
    bf16*  embW   = (bf16*)pC;
    float* gh_w   = (float*)(pC + 27000000);
    bf16*  xw_w1  = (bf16*)(pC + 27000000 + 27648000);
    bf16*  xw_ch  = (bf16*)pC;                        // sentence phase overlay
    float* h_w0   = (float*)pF;
    float* h_w1   = (float*)pG;
    // sentence h double-buffers (overlay pG after h_w1 dies); 716,800 B each
    float* hs0a = (float*)pG;
    float* hs0b = (float*)(pG + 716800);
    float* hs1a = (float*)(pG + 1433600);
    float* hs1b = (float*)(pG + 2150400);

    hipMemsetAsync(ws, 0, total, stream);  // poison kill + h0 = 0

    auto grid = [](int M, int Nc) {
        return dim3((Nc + TN - 1) / TN, (M + TM - 1) / TM, 2);
    };

    // ===================== word encoder =====================
    gemm_aw<float, float, bf16><<<grid(V, Gw), 256, 0, stream>>>(
        emb, 0, we_Wih0, (long)Gw * E, embW, (long)V * Gw, V, Gw, E);
    for (int k = 0; k < T; ++k) {
        gemm_aw<float, float, float><<<grid(Nw, Gw), 256, 0, stream>>>(
            h_w0, (long)Nw * HW, we_Whh0, (long)Gw * HW, gh_w, (long)Nw * Gw, Nw, Gw, HW);
        long tot = 2ll * Nw * HW;
        gru_step_word0<<<(tot + 255) / 256, 256, 0, stream>>>(
            x, embW, gh_w, we_bih0, we_bhh0, h_w0, y0w, S, T, B, V, HW, k);
    }
    for (int k = 0; k < T; ++k) {
        gemm_aw<bf16, float, bf16><<<grid(Nw, Gw), 256, 0, stream>>>(
            y0w + (long)k * Nw * 2 * HW, (long)(T - 1 - 2 * k) * Nw * 2 * HW,
            we_Wih1, (long)Gw * (2 * HW), xw_w1, (long)Nw * Gw, Nw, Gw, 2 * HW);
        gemm_aw<float, float, float><<<grid(Nw, Gw), 256, 0, stream>>>(
            h_w1, (long)Nw * HW, we_Whh1, (long)Gw * HW, gh_w, (long)Nw * Gw, Nw, Gw, HW);
        long tot = 2ll * Nw * HW;
        gru_step1<<<(tot + 255) / 256, 256, 0, stream>>>(
            xw_w1, k, T - 1 - k, 1, gh_w, we_bih1, we_bhh1, h_w1, nullptr, Nw, HW, T, k);
    }
    {
        long tot = (long)Nw * 4 * HW;
        concat4<bf16><<<(tot + 255) / 256, 256, 0, stream>>>(h_w0, h_w1, words, Nw, HW);
    }

    // ===================== sentence encoder (fused steps) =====================
    hipMemsetAsync(pG, 0, 2867200, stream);  // zero all 4 h buffers

    const dim3 sgrid(100, 1, 2);   // 100 j-tiles x 2 dirs

    // ---- layer 0 ----
    for (int c = 0; c < 2; ++c) {
        int tb0 = c * CH, tb1 = S - c * CH - CH;
        gemm_aw<bf16, float, bf16><<<grid(CH * B, Gs), 256, 0, stream>>>(
            words + (long)tb0 * B * (4 * HW), (long)(tb1 - tb0) * B * (4 * HW),
            se_Wih0, (long)Gs * (4 * HW), xw_ch, (long)CH * B * Gs, CH * B, Gs, 4 * HW);
        for (int k = c * CH; k < c * CH + CH; ++k) {
            const float* hRb = (k & 1) ? hs0b : hs0a;
            float*       hWb = (k & 1) ? hs0a : hs0b;
            step_fused<<<sgrid, 256, 0, stream>>>(
                se_Whh0, se_bih0, se_bhh0, xw_ch, hRb, hWb, y0s, k, tb0, tb1);
        }
    }
    // ---- layer 1 ----
    for (int c = 0; c < 2; ++c) {
        int tb0 = c * CH, tb1 = S - c * CH - CH;
        gemm_aw<bf16, float, bf16><<<grid(CH * B, Gs), 256, 0, stream>>>(
            y0s + (long)tb0 * B * (2 * HS), (long)(tb1 - tb0) * B * (2 * HS),
            se_Wih1, (long)Gs * (2 * HS), xw_ch, (long)CH * B * Gs, CH * B, Gs, 2 * HS);
        for (int k = c * CH; k < c * CH + CH; ++k) {
            const float* hRb = (k & 1) ? hs1b : hs1a;
            float*       hWb = (k & 1) ? hs1a : hs1b;
            step_fused<<<sgrid, 256, 0, stream>>>(
                se_Whh1, se_bih1, se_bhh1, xw_ch, hRb, hWb, nullptr, k, tb0, tb1);
        }
    }

    // out[1, B, 4*HS] = [sf0 | sb0 | sf1 | sb1]  (float32); 120 steps -> result in *a bufs
    {
        long tot = (long)B * 4 * HS;
        concat4<float><<<(tot + 255) / 256, 256, 0, stream>>>(hs0a, hs1a, (float*)d_out, B, HS);
    }
}